// Round 7
// baseline (222.994 us; speedup 1.0000x reference)
//
#include <hip/hip_runtime.h>

// EMA recurrence: out[t] = a*x[t] + (1-a)*out[t-1] over T=4096 (contiguous),
// 8192 independent sequences [B=8, D=1024, T=4096] fp32.
//
// R12 = R11 (best, 218.4 us) with the serial shuffle chains replaced by
// ONE parallel DS round.
//   R11's per-wave tail: 3 dependent Kogge-Stone shfl_up levels + a
//   dependent lane-7 broadcast = 4 serial DS round-trips (~160 cy) during
//   which the store cannot issue. But the exclusive carry is just a
//   fixed-weight sum over the 7 preceding lane-tails, and h_in is a
//   fixed-weight sum over lanes 0-7's warm-up tails:
//     excl = sum_{k=1..7} b^(4(k-1)) * c3(lane-k)
//     h_in = sum_{j=0..7} b^(4(7-j)) * d3(j)
//   So: 7 shfl_up(c3,k) + 8 shfl(d3,j) -- all 15 INDEPENDENT, one DS
//   round-trip -- then depth-3 fma trees. Same truncation (history > 32
//   floats dropped, weight <= b^32 ~ 8.4e-8), same traffic, same grid;
//   only reassociation of the same weighted sums.
//
// Session ladder: R5/R11 256-float tiles, 131072 waves -> 222.5/218.4 us
// (best); R6/R7 512-float supertiles -> 228.6; R8 persistent -> 232.2
// (latency-bound: 31% BW, VALUBusy 4.5%). Churn structure is settled;
// this attacks the last in-wave serial latency.
//
// Design: one wave per 256-float tile, ZERO inter-tile dependency.
// Coalesced 64xfloat4 tile load + lanes 0-7 load the preceding 8 float4
// (warm-up, mostly L2-hit), lane-local 4-elem scan, one parallel shuffle
// round, weighted-sum epilogue, coalesced float4 store, exit.

constexpr int TILES_PER_SEQ = 16;    // 4096 / 256

__global__ __launch_bounds__(256) void ema_tile_kernel(
    const float* __restrict__ x,
    const float* __restrict__ h0,
    float* __restrict__ out,
    int ntiles)
{
    const int gtid = blockIdx.x * blockDim.x + threadIdx.x;
    const int w    = gtid >> 6;      // global tile index = wave index
    const int lane = threadIdx.x & 63;
    if (w >= ntiles) return;

    const int tidx = w & (TILES_PER_SEQ - 1);
    const int seq  = w >> 4;

    const float a   = 0.4f;
    const float b   = 0.6f;
    const float b2  = b * b;
    const float b3  = b2 * b;
    const float b4  = b2 * b2;
    const float b8  = b4 * b4;
    const float b16 = b8 * b8;
    const float b24 = b16 * b8;
    // b^(4*lane): carry-in scale; underflows to 0 beyond lane ~20 (truncation).
    const float pb4i = exp2f((float)(4 * lane) * -0.73696559416f);

    const float4* __restrict__ xp = (const float4*)x;
    float4* __restrict__ op       = (float4*)out;

    // All flat indices in size_t BEFORE pointer arithmetic.
    const size_t tile_base = (size_t)w * 64;

    // Main tile load: lane i gets floats [w*256 + 4i, ...+4). Fully coalesced.
    float4 v = xp[tile_base + (size_t)lane];

    // Warm-up load: previous 32 floats, lanes 0-7 (wave-uniform branch).
    const bool has_warm = (tidx != 0);
    float4 wv = make_float4(0.f, 0.f, 0.f, 0.f);
    if (has_warm && lane < 8) {
        wv = xp[tile_base - 8 + (size_t)lane];   // tile_base >= 64 here
    }

    // --- main lane-local scan (zero-init): c_j = a*x_j + b*c_{j-1} ---
    float c0 = a * v.x;
    float c1 = fmaf(b, c0, a * v.y);
    float c2 = fmaf(b, c1, a * v.z);
    float c3 = fmaf(b, c2, a * v.w);

    // --- warm-up lane-local scan (zero-init), independent chain ---
    float d0 = a * wv.x;
    float d1 = fmaf(b, d0, a * wv.y);
    float d2 = fmaf(b, d1, a * wv.z);
    float d3 = fmaf(b, d2, a * wv.w);

    // --- ONE parallel shuffle round: 15 independent DS ops ---
    float u1 = __shfl_up(c3, 1, 64);
    float u2 = __shfl_up(c3, 2, 64);
    float u3 = __shfl_up(c3, 3, 64);
    float u4 = __shfl_up(c3, 4, 64);
    float u5 = __shfl_up(c3, 5, 64);
    float u6 = __shfl_up(c3, 6, 64);
    float u7 = __shfl_up(c3, 7, 64);
    float s0 = __shfl(d3, 0, 64);
    float s1 = __shfl(d3, 1, 64);
    float s2 = __shfl(d3, 2, 64);
    float s3 = __shfl(d3, 3, 64);
    float s4 = __shfl(d3, 4, 64);
    float s5 = __shfl(d3, 5, 64);
    float s6 = __shfl(d3, 6, 64);
    float s7 = __shfl(d3, 7, 64);

    // Mask out-of-range shfl_up results (lane < k returns own value).
    u1 = (lane >= 1) ? u1 : 0.0f;
    u2 = (lane >= 2) ? u2 : 0.0f;
    u3 = (lane >= 3) ? u3 : 0.0f;
    u4 = (lane >= 4) ? u4 : 0.0f;
    u5 = (lane >= 5) ? u5 : 0.0f;
    u6 = (lane >= 6) ? u6 : 0.0f;
    u7 = (lane >= 7) ? u7 : 0.0f;

    // excl = sum_{k=1..7} b^(4(k-1)) u_k   (depth-3 fma tree)
    float p01 = fmaf(b4, u2, u1);        // u1 + b4 u2
    float p23 = fmaf(b4, u4, u3);        // u3 + b4 u4
    float p45 = fmaf(b4, u6, u5);        // u5 + b4 u6
    float p457 = fmaf(b8, u7, p45);      // u5 + b4 u6 + b8 u7
    float excl = fmaf(b8, p23, p01);
    excl = fmaf(b16, p457, excl);

    // --- incoming state h_in (all lanes compute it locally; no broadcast) ---
    float h_in;
    if (has_warm) {
        // h_in = sum_{j=0..7} b^(4(7-j)) s_j   (depth-3 fma tree)
        float q76 = fmaf(b4, s6, s7);
        float q54 = fmaf(b4, s4, s5);
        float q32 = fmaf(b4, s2, s3);
        float q10 = fmaf(b4, s0, s1);
        float qh  = fmaf(b8, q10, q32);
        h_in = fmaf(b8, q54, q76);
        h_in = fmaf(b16, qh, h_in);
    } else {
        h_in = h0[(size_t)seq];      // true initial hidden state (wave-uniform)
    }

    // Exclusive carry into this lane (dropped term <= b^28 ~ 6e-7).
    float e = fmaf(pb4i, h_in, excl);

    float4 o;
    o.x = fmaf(b , e, c0);
    o.y = fmaf(b2, e, c1);
    o.z = fmaf(b3, e, c2);
    o.w = fmaf(b4, e, c3);
    op[tile_base + (size_t)lane] = o;
}

extern "C" void kernel_launch(void* const* d_in, const int* in_sizes, int n_in,
                              void* d_out, int out_size, void* d_ws, size_t ws_size,
                              hipStream_t stream) {
    const float* x  = (const float*)d_in[0];   // [8,1024,4096] fp32
    const float* h0 = (const float*)d_in[1];   // [8,1024,1]    fp32
    float* out = (float*)d_out;                // [8,1024,4096] fp32

    const int nseq   = in_sizes[1];            // 8192 sequences
    const int ntiles = nseq * TILES_PER_SEQ;   // 131072 waves
    const int block  = 256;                    // 4 waves/block
    const long long total = (long long)ntiles * 64;
    const int grid = (int)((total + block - 1) / block);  // 32768 blocks

    ema_tile_kernel<<<grid, block, 0, stream>>>(x, h0, out, ntiles);
}

// Round 8
// 221.042 us; speedup vs baseline: 1.0088x; 1.0088x over previous
//
#include <hip/hip_runtime.h>

// EMA recurrence: out[t] = a*x[t] + (1-a)*out[t-1] over T=4096 (contiguous),
// 8192 independent sequences [B=8, D=1024, T=4096] fp32.
//
// R13 = R11 (best, 218.4 us) with the warm-up cross-lane work moved OFF
// the DS pipe. R12's lesson: with 131072 churning waves, latency is
// hidden by wave parallelism -- per-wave op count on the contended pipe
// is what matters (R12 added 8 DS ops to shorten the chain: +4.6 us).
// R11 spent 7 DS ops/wave: 3 (main KS) + 3 (warm-up KS) + 1 (broadcast).
// The warm-up result h_in = sum_j b^(4(7-j)) d3_j is WAVE-UNIFORM, so it
// can be built from v_readlane (VALU->SGPR, not DS) + an 8-fma Horner
// chain on the ~95%-idle VALU pipe (R8 counters). DS ops: 7 -> 3/wave.
// Main KS stays at its minimum 3 shuffles (coarser truncation would cost
// accuracy). Numerics: same weights, reassociated -- same truncation
// (history > 32 floats dropped, weight <= b^32 ~ 8.4e-8).
//
// Session ladder: R5/R11 256-float tiles, max churn -> 222.5/218.4 (best);
// R6/R7 512-float supertiles -> 228.6; R8 persistent -> 232.2 (31% BW,
// VALUBusy 4.5%, latency-bound); R12 parallel-DS -> 223.0 (+8 DS ops).
//
// Design: one wave per 256-float tile, ZERO inter-tile dependency.
// Coalesced 64xfloat4 tile load + lanes 0-7 load the preceding 8 float4
// (warm-up, mostly L2-hit), lane-local 4-elem scans, 3-shuffle KS,
// readlane-based uniform h_in, coalesced float4 store, exit.
// NOTE: grid is exact (ntiles*64 threads), so all 64 lanes of every wave
// are active -- readlane from lanes 0-7 is always well-defined.

constexpr int TILES_PER_SEQ = 16;    // 4096 / 256

__device__ __forceinline__ float lane_f32(float v, int l) {
    return __uint_as_float(__builtin_amdgcn_readlane(__float_as_uint(v), l));
}

__global__ __launch_bounds__(256) void ema_tile_kernel(
    const float* __restrict__ x,
    const float* __restrict__ h0,
    float* __restrict__ out,
    int ntiles)
{
    const int gtid = blockIdx.x * blockDim.x + threadIdx.x;
    const int w    = gtid >> 6;      // global tile index = wave index
    const int lane = threadIdx.x & 63;
    if (w >= ntiles) return;         // never fires (exact grid); kept for safety

    const int tidx = w & (TILES_PER_SEQ - 1);
    const int seq  = w >> 4;

    const float a   = 0.4f;
    const float b   = 0.6f;
    const float b2  = b * b;
    const float b3  = b2 * b;
    const float b4  = b2 * b2;
    const float b8  = b4 * b4;
    const float b16 = b8 * b8;
    const float inv_b4 = 1.0f / b4;

    // Kogge-Stone step multipliers (0 where no source at that distance).
    const float m1 = (lane >= 1) ? b4  : 0.0f;
    const float m2 = (lane >= 2) ? b8  : 0.0f;
    const float m3 = (lane >= 4) ? b16 : 0.0f;
    // b^(4*lane): carry-in scale; underflows to 0 beyond lane ~20 (truncation).
    const float pb4i = exp2f((float)(4 * lane) * -0.73696559416f);

    const float4* __restrict__ xp = (const float4*)x;
    float4* __restrict__ op       = (float4*)out;

    // All flat indices in size_t BEFORE pointer arithmetic.
    const size_t tile_base = (size_t)w * 64;

    // Main tile load: lane i gets floats [w*256 + 4i, ...+4). Fully coalesced.
    float4 v = xp[tile_base + (size_t)lane];

    // Warm-up load: previous 32 floats, lanes 0-7 (wave-uniform branch).
    const bool has_warm = (tidx != 0);
    float4 wv = make_float4(0.f, 0.f, 0.f, 0.f);
    if (has_warm && lane < 8) {
        wv = xp[tile_base - 8 + (size_t)lane];   // tile_base >= 64 here
    }

    // --- main lane-local scan (zero-init): c_j = a*x_j + b*c_{j-1} ---
    float c0 = a * v.x;
    float c1 = fmaf(b, c0, a * v.y);
    float c2 = fmaf(b, c1, a * v.z);
    float c3 = fmaf(b, c2, a * v.w);

    // --- warm-up lane-local scan (zero-init), independent chain ---
    float d0 = a * wv.x;
    float d1 = fmaf(b, d0, a * wv.y);
    float d2 = fmaf(b, d1, a * wv.z);
    float d3 = fmaf(b, d2, a * wv.w);

    // --- main KS over lane tails (dist k weight b^(4k), trunc b^32) ---
    // 3 DS ops total per wave; this is the whole DS budget now.
    float t = c3, u;
    u = __shfl_up(t, 1, 64); t = fmaf(m1, u, t);
    u = __shfl_up(t, 2, 64); t = fmaf(m2, u, t);
    u = __shfl_up(t, 4, 64); t = fmaf(m3, u, t);

    // --- incoming state h_in: wave-uniform, built via readlane (no DS) ---
    // h_in = sum_{j=0..7} b^(4(7-j)) * d3_j   (Horner over j)
    float h_in;
    if (has_warm) {
        float h = lane_f32(d3, 0);
        h = fmaf(b4, h, lane_f32(d3, 1));
        h = fmaf(b4, h, lane_f32(d3, 2));
        h = fmaf(b4, h, lane_f32(d3, 3));
        h = fmaf(b4, h, lane_f32(d3, 4));
        h = fmaf(b4, h, lane_f32(d3, 5));
        h = fmaf(b4, h, lane_f32(d3, 6));
        h = fmaf(b4, h, lane_f32(d3, 7));
        h_in = h;
    } else {
        h_in = h0[(size_t)seq];      // true initial hidden state (wave-uniform)
    }

    // Exclusive tail recovered algebraically (dropped term <= b^28 ~ 6e-7).
    float e = fmaf(pb4i, h_in, (t - c3) * inv_b4);

    float4 o;
    o.x = fmaf(b , e, c0);
    o.y = fmaf(b2, e, c1);
    o.z = fmaf(b3, e, c2);
    o.w = fmaf(b4, e, c3);
    op[tile_base + (size_t)lane] = o;
}

extern "C" void kernel_launch(void* const* d_in, const int* in_sizes, int n_in,
                              void* d_out, int out_size, void* d_ws, size_t ws_size,
                              hipStream_t stream) {
    const float* x  = (const float*)d_in[0];   // [8,1024,4096] fp32
    const float* h0 = (const float*)d_in[1];   // [8,1024,1]    fp32
    float* out = (float*)d_out;                // [8,1024,4096] fp32

    const int nseq   = in_sizes[1];            // 8192 sequences
    const int ntiles = nseq * TILES_PER_SEQ;   // 131072 waves
    const int block  = 256;                    // 4 waves/block
    const long long total = (long long)ntiles * 64;
    const int grid = (int)((total + block - 1) / block);  // 32768 blocks

    ema_tile_kernel<<<grid, block, 0, stream>>>(x, h0, out, ntiles);
}

// Round 9
// 218.629 us; speedup vs baseline: 1.0200x; 1.0110x over previous
//
#include <hip/hip_runtime.h>

// EMA recurrence: out[t] = a*x[t] + (1-a)*out[t-1] over T=4096 (contiguous),
// 8192 independent sequences [B=8, D=1024, T=4096] fp32.
//
// R14 = final restore of R11 (the session's measured-best source: 218.4 us;
// same source measured 222.5 in round 0 -- defines a +-4 us identical-source
// noise band).
//
// Complete session ladder (dur_us; fills ~161 us of each measurement at
// 83-85% of HBM peak -- uncontrollable harness reset traffic):
//   R5/R11 256-float tiles, 131072 short-lived waves  -> 222.5 / 218.4 BEST
//   R6/R7  512-float supertiles (+-nt stores)         -> 228.6 / 228.6
//   R8     persistent, 1 wave/seq (8192 waves)        -> 232.2
//            counters: 2.46 TB/s = 31% peak, VALUBusy 4.5% -> latency-bound
//   R12    parallel 15-shuffle DS round (chain-depth) -> 223.0 (noise)
//   R13    readlane warm-up, DS 7->3/wave (op-count)  -> 221.0 (noise)
// Conclusions:
//   - Wave churn (loads issued at wave birth, exit after store) hides
//     latency better than any in-wave pipelining; 256-float tiles are the
//     churn maximum subject to full float4/lane coalescing.
//   - Micro-op perturbations of the epilogue (DS count, chain depth,
//     readlane vs shuffle) are invisible at +-4 us noise: the kernel is
//     bound by its memory streams + wave-launch pipeline, running at ~75%
//     of the measured copy ceiling (ema ~57 us vs 42.7 us traffic floor).
//
// Design: one wave per 256-float tile, ZERO inter-tile dependency.
//   - Coalesced 64xfloat4 tile load + lanes 0-7 load the preceding 8
//     float4 (warm-up, mostly L2-hit), lane-local scan + Kogge-Stone
//     (3 shuffles), 1 broadcast, coalesced float4 store, exit.
//   - Decay truncation: history older than 32 elements carries weight
//     0.6^32 ~ 8.4e-8 (abs threshold 5.5e-2). Warm-up scan from h=0 over
//     the previous 32 floats replaces the sequential carry. Tile 0 of
//     each sequence uses the true hidden init.

constexpr int TILES_PER_SEQ = 16;    // 4096 / 256

__global__ __launch_bounds__(256) void ema_tile_kernel(
    const float* __restrict__ x,
    const float* __restrict__ h0,
    float* __restrict__ out,
    int ntiles)
{
    const int gtid = blockIdx.x * blockDim.x + threadIdx.x;
    const int w    = gtid >> 6;      // global tile index = wave index
    const int lane = threadIdx.x & 63;
    if (w >= ntiles) return;

    const int tidx = w & (TILES_PER_SEQ - 1);
    const int seq  = w >> 4;

    const float a   = 0.4f;
    const float b   = 0.6f;
    const float b2  = b * b;
    const float b3  = b2 * b;
    const float b4  = b2 * b2;
    const float b8  = b4 * b4;
    const float b16 = b8 * b8;
    const float inv_b4 = 1.0f / b4;

    // Kogge-Stone step multipliers (0 where no source at that distance).
    const float m1 = (lane >= 1) ? b4  : 0.0f;
    const float m2 = (lane >= 2) ? b8  : 0.0f;
    const float m3 = (lane >= 4) ? b16 : 0.0f;
    // b^(4*lane): carry-in scale; underflows to 0 beyond lane ~20 (truncation).
    const float pb4i = exp2f((float)(4 * lane) * -0.73696559416f);

    const float4* __restrict__ xp = (const float4*)x;
    float4* __restrict__ op       = (float4*)out;

    // All flat indices in size_t BEFORE pointer arithmetic.
    const size_t tile_base = (size_t)w * 64;

    // Main tile load: lane i gets floats [w*256 + 4i, ...+4). Fully coalesced.
    float4 v = xp[tile_base + (size_t)lane];

    // Warm-up load: previous 32 floats, lanes 0-7 (wave-uniform branch).
    const bool has_warm = (tidx != 0);
    float4 wv = make_float4(0.f, 0.f, 0.f, 0.f);
    if (has_warm && lane < 8) {
        wv = xp[tile_base - 8 + (size_t)lane];   // tile_base >= 64 here
    }

    // --- main lane-local scan (zero-init): c_j = a*x_j + b*c_{j-1} ---
    float c0 = a * v.x;
    float c1 = fmaf(b, c0, a * v.y);
    float c2 = fmaf(b, c1, a * v.z);
    float c3 = fmaf(b, c2, a * v.w);

    // KS over lane tails (distance k weight b^(4k), truncated at b^32).
    float t = c3, u;
    u = __shfl_up(t, 1, 64); t = fmaf(m1, u, t);
    u = __shfl_up(t, 2, 64); t = fmaf(m2, u, t);
    u = __shfl_up(t, 4, 64); t = fmaf(m3, u, t);

    // --- incoming state h_in at tile start ---
    float h_in;
    if (has_warm) {
        // Scan the 32 warm-up floats (lanes 0-7) from h=0; take lane 7's tail.
        float d0 = a * wv.x;
        float d1 = fmaf(b, d0, a * wv.y);
        float d2 = fmaf(b, d1, a * wv.z);
        float d3 = fmaf(b, d2, a * wv.w);
        float tw = d3;
        u = __shfl_up(tw, 1, 64); tw = fmaf(m1, u, tw);
        u = __shfl_up(tw, 2, 64); tw = fmaf(m2, u, tw);
        u = __shfl_up(tw, 4, 64); tw = fmaf(m3, u, tw);
        h_in = __shfl(tw, 7, 64);
    } else {
        h_in = h0[(size_t)seq];      // true initial hidden state (wave-uniform)
    }

    // Exclusive tail recovered algebraically (dropped term <= b^28 ~ 6e-7).
    float e = fmaf(pb4i, h_in, (t - c3) * inv_b4);

    float4 o;
    o.x = fmaf(b , e, c0);
    o.y = fmaf(b2, e, c1);
    o.z = fmaf(b3, e, c2);
    o.w = fmaf(b4, e, c3);
    op[tile_base + (size_t)lane] = o;
}

extern "C" void kernel_launch(void* const* d_in, const int* in_sizes, int n_in,
                              void* d_out, int out_size, void* d_ws, size_t ws_size,
                              hipStream_t stream) {
    const float* x  = (const float*)d_in[0];   // [8,1024,4096] fp32
    const float* h0 = (const float*)d_in[1];   // [8,1024,1]    fp32
    float* out = (float*)d_out;                // [8,1024,4096] fp32

    const int nseq   = in_sizes[1];            // 8192 sequences
    const int ntiles = nseq * TILES_PER_SEQ;   // 131072 waves
    const int block  = 256;                    // 4 waves/block
    const long long total = (long long)ntiles * 64;
    const int grid = (int)((total + block - 1) / block);  // 32768 blocks

    ema_tile_kernel<<<grid, block, 0, stream>>>(x, h0, out, ntiles);
}